// Round 1
// baseline (263.510 us; speedup 1.0000x reference)
//
#include <hip/hip_runtime.h>
#include <hip/hip_bf16.h>
#include <cstdint>

#define NQ 256
#define NK 2048
#define BB 2
#define SCALE 0.17677669529663687f  // 32^-0.5

// ws byte offsets (16B aligned)
#define TB_OFF 0u         // ushort[64000]  bf16 tables [i][z][y][x][h]   128000 B
#define QP_OFF 128000u    // float[131072]  q-proj (B,nQ,256), pre-scaled 524288 B
#define KT_OFF 652288u    // float[131072]  k-proj transposed (B,32,nK)   524288 B
#define VP_OFF 1176576u   // float[131072]  v-proj (B,nK,32)              524288 B
#define XP_OFF 1700864u   // float[1048576] attn@v partials [kc][b,h,q,d] 4 MB

typedef unsigned short u16;

static __device__ __forceinline__ float blo(uint32_t u) { return __uint_as_float(u << 16); }
static __device__ __forceinline__ float bhi(uint32_t u) { return __uint_as_float(u & 0xffff0000u); }

static __device__ __forceinline__ u16 f2bf(float f) {
  union { float f; uint32_t u; } v; v.f = f;
  uint32_t r = (v.u + 0x7fffu + ((v.u >> 16) & 1u)) >> 16;
  return (u16)r;
}

// ---------------- kernel 0: CPB MLP -> bf16 tables ----------------
__global__ __launch_bounds__(256) void k_tables(const float* __restrict__ w1g,
                                                const float* __restrict__ b1g,
                                                const float* __restrict__ w2g,
                                                u16* __restrict__ tb) {
  __shared__ float w1[384];
  __shared__ float b1[128];
  __shared__ float w2[1024];
  int i = blockIdx.x >> 2, cc = blockIdx.x & 3, t = threadIdx.x;
  for (int idx = t; idx < 384; idx += 256) w1[idx] = w1g[i * 384 + idx];
  if (t < 128) b1[t] = b1g[i * 128 + t];
  for (int idx = t; idx < 1024; idx += 256) w2[idx] = w2g[i * 1024 + idx];
  __syncthreads();
  int cell = cc * 250 + t;
  if (t < 250) {
    int z = cell / 100, y = (cell / 10) % 10, x = cell % 10;
    const float step = 8.0f / 9.0f;
    float cz = -4.f + z * step, cy = -4.f + y * step, cx = -4.f + x * step;
    float o0 = 0, o1 = 0, o2 = 0, o3 = 0, o4 = 0, o5 = 0, o6 = 0, o7 = 0;
    for (int d = 0; d < 128; ++d) {
      float h = fmaxf(fmaf(cz, w1[d], fmaf(cy, w1[128 + d], fmaf(cx, w1[256 + d], b1[d]))), 0.f);
      const float* w2r = &w2[d * 8];
      o0 = fmaf(h, w2r[0], o0); o1 = fmaf(h, w2r[1], o1);
      o2 = fmaf(h, w2r[2], o2); o3 = fmaf(h, w2r[3], o3);
      o4 = fmaf(h, w2r[4], o4); o5 = fmaf(h, w2r[5], o5);
      o6 = fmaf(h, w2r[6], o6); o7 = fmaf(h, w2r[7], o7);
    }
    u16 r[8] = { f2bf(o0), f2bf(o1), f2bf(o2), f2bf(o3),
                 f2bf(o4), f2bf(o5), f2bf(o6), f2bf(o7) };
    *(uint4*)&tb[i * 8000 + cell * 8] = *(const uint4*)r;
  }
}

// ---------------- kernel 1: K/V projections ----------------
// kpT[b][d][k] (transposed, for coalesced d-major reads), vp[b][k][d]
__global__ __launch_bounds__(512) void k_kv(const float* __restrict__ key,
                                            const float* __restrict__ kw,
                                            const float* __restrict__ kb,
                                            const float* __restrict__ vw,
                                            const float* __restrict__ vb,
                                            float* __restrict__ kpT,
                                            float* __restrict__ vp) {
  __shared__ float rows[16][257];
  int b = blockIdx.x >> 7, kc = blockIdx.x & 127, t = threadIdx.x;
  for (int idx = t; idx < 4096; idx += 512) {
    int r = idx >> 8, m = idx & 255;
    rows[r][m] = key[((kc * 16 + r) * BB + b) * 256 + m];
  }
  __syncthreads();
  int ks = t >> 5, d = t & 31;
  float a = kb[d], av = vb[d];
  #pragma unroll 4
  for (int m = 0; m < 256; ++m) {
    float rv = rows[ks][m];
    a  = fmaf(rv, kw[m * 32 + d], a);
    av = fmaf(rv, vw[m * 32 + d], av);
  }
  int k = kc * 16 + ks;
  kpT[(b * 32 + d) * NK + k] = a;
  vp[(b * NK + k) * 32 + d] = av;
}

// ---------------- kernel 2: Q projection (pre-scaled) ----------------
__global__ __launch_bounds__(256) void k_q(const float* __restrict__ query,
                                           const float* __restrict__ qw,
                                           const float* __restrict__ qb,
                                           float* __restrict__ qp) {
  __shared__ float rows[4][257];
  int b = blockIdx.x >> 6, qc = blockIdx.x & 63, t = threadIdx.x;
  for (int idx = t; idx < 1024; idx += 256) {
    int r = idx >> 8, m = idx & 255;
    rows[r][m] = query[((qc * 4 + r) * BB + b) * 256 + m];
  }
  __syncthreads();
  int r = t >> 6, c0 = (t & 63) * 4;
  float4 acc = *(const float4*)&qb[c0];
  #pragma unroll 4
  for (int m = 0; m < 256; ++m) {
    float rv = rows[r][m];
    float4 w4 = *(const float4*)&qw[m * 256 + c0];
    acc.x = fmaf(rv, w4.x, acc.x); acc.y = fmaf(rv, w4.y, acc.y);
    acc.z = fmaf(rv, w4.z, acc.z); acc.w = fmaf(rv, w4.w, acc.w);
  }
  int q = qc * 4 + r;
  float4 o; o.x = acc.x * SCALE; o.y = acc.y * SCALE; o.z = acc.z * SCALE; o.w = acc.w * SCALE;
  *(float4*)&qp[(b * 256 + q) * 256 + c0] = o;
}

// ---------------- kernel 3: fused qk + rpe + softmax -> attn ----------------
struct Axis { int o0, o1; float w0, w1; };

static __device__ __forceinline__ Axis axis_setup(float dv, int stride) {
  float g = copysignf(__log2f(fmaf(fabsf(dv), 512.f, 1.f)) * (1.f / 12.f), dv);
  float p = fmaf(g, 4.5f, 4.5f);
  float f = floorf(p);
  int i0 = (int)f;
  float w1v = p - f;
  float w0v = 1.f - w1v;
  Axis a;
  a.w0 = ((unsigned)i0 <= 9u) ? w0v : 0.f;
  a.w1 = ((unsigned)(i0 + 1) <= 9u) ? w1v : 0.f;
  int c0 = min(max(i0, 0), 9);
  int c1 = min(max(i0 + 1, 0), 9);
  a.o0 = c0 * stride;
  a.o1 = c1 * stride;
  return a;
}

#define DO_CORNER(U, W) do { float ww = (W); \
  acc[0][j] = fmaf(blo((U).x), ww, acc[0][j]); \
  acc[1][j] = fmaf(bhi((U).x), ww, acc[1][j]); \
  acc[2][j] = fmaf(blo((U).y), ww, acc[2][j]); \
  acc[3][j] = fmaf(bhi((U).y), ww, acc[3][j]); \
  acc[4][j] = fmaf(blo((U).z), ww, acc[4][j]); \
  acc[5][j] = fmaf(bhi((U).z), ww, acc[5][j]); \
  acc[6][j] = fmaf(blo((U).w), ww, acc[6][j]); \
  acc[7][j] = fmaf(bhi((U).w), ww, acc[7][j]); } while (0)

__global__ __launch_bounds__(512) void k_main(const u16* __restrict__ tbw,
                                              const float* __restrict__ qp,
                                              const float* __restrict__ kpT,
                                              const float* __restrict__ xyz,
                                              const float* __restrict__ refp,
                                              float* __restrict__ attn) {
  __shared__ __align__(16) u16 tb[64000];    // 125 KB bf16 tables
  __shared__ __align__(16) float qrow[256];
  __shared__ __align__(16) float rp[24];
  __shared__ __align__(16) float red[64];    // [h][wave]
  int t = threadIdx.x;
  int b = blockIdx.x >> 8, q = blockIdx.x & 255;
  for (int idx = t; idx < 8000; idx += 512)
    ((uint4*)tb)[idx] = ((const uint4*)tbw)[idx];
  if (t < 64) ((float4*)qrow)[t] = ((const float4*)(qp + (b * 256 + q) * 256))[t];
  if (t >= 64 && t < 70) ((float4*)rp)[t - 64] = ((const float4*)(refp + (b * 256 + q) * 24))[t - 64];
  __syncthreads();

  float rpr[24];
  #pragma unroll
  for (int c4 = 0; c4 < 6; ++c4) {
    float4 v = *(const float4*)&rp[c4 * 4];
    rpr[c4 * 4 + 0] = v.x; rpr[c4 * 4 + 1] = v.y; rpr[c4 * 4 + 2] = v.z; rpr[c4 * 4 + 3] = v.w;
  }

  int wv = t >> 6, l = t & 63;
  int k0 = wv * 256 + l * 4;   // 4 consecutive k per thread
  float acc[8][4] = {};

  // phase 1: qk^T (q pre-scaled)
  const float* kT = kpT + b * (32 * NK);
  #pragma unroll 1
  for (int dq = 0; dq < 8; ++dq) {
    const float* kp0 = kT + (dq * 4) * NK + k0;
    float4 kv0 = *(const float4*)(kp0);
    float4 kv1 = *(const float4*)(kp0 + NK);
    float4 kv2 = *(const float4*)(kp0 + 2 * NK);
    float4 kv3 = *(const float4*)(kp0 + 3 * NK);
    #pragma unroll
    for (int h = 0; h < 8; ++h) {
      float4 qv = *(const float4*)&qrow[h * 32 + dq * 4];
      acc[h][0] = fmaf(qv.x, kv0.x, fmaf(qv.y, kv1.x, fmaf(qv.z, kv2.x, fmaf(qv.w, kv3.x, acc[h][0]))));
      acc[h][1] = fmaf(qv.x, kv0.y, fmaf(qv.y, kv1.y, fmaf(qv.z, kv2.y, fmaf(qv.w, kv3.y, acc[h][1]))));
      acc[h][2] = fmaf(qv.x, kv0.z, fmaf(qv.y, kv1.z, fmaf(qv.z, kv2.z, fmaf(qv.w, kv3.z, acc[h][2]))));
      acc[h][3] = fmaf(qv.x, kv0.w, fmaf(qv.y, kv1.w, fmaf(qv.z, kv2.w, fmaf(qv.w, kv3.w, acc[h][3]))));
    }
  }

  // phase 2: rpe trilinear sampling, accumulate into logits
  #pragma unroll
  for (int j = 0; j < 4; ++j) {
    int k = k0 + j;
    const float* xp = xyz + (b * NK + k) * 3;
    float xv = xp[0], yv = xp[1], zv = xp[2];
    #pragma unroll 1
    for (int i = 0; i < 8; ++i) {
      float dxv = rpr[i * 3 + 0] - xv;
      float dyv = rpr[i * 3 + 1] - yv;
      float dzv = rpr[i * 3 + 2] - zv;
      Axis ax = axis_setup(dxv, 8);
      Axis ay = axis_setup(dyv, 80);
      Axis az = axis_setup(dzv, 800);
      float w00 = az.w0 * ay.w0, w01 = az.w0 * ay.w1;
      float w10 = az.w1 * ay.w0, w11 = az.w1 * ay.w1;
      const u16* tp = tb + i * 8000;
      uint4 u;
      u = *(const uint4*)(tp + az.o0 + ay.o0 + ax.o0); DO_CORNER(u, w00 * ax.w0);
      u = *(const uint4*)(tp + az.o0 + ay.o0 + ax.o1); DO_CORNER(u, w00 * ax.w1);
      u = *(const uint4*)(tp + az.o0 + ay.o1 + ax.o0); DO_CORNER(u, w01 * ax.w0);
      u = *(const uint4*)(tp + az.o0 + ay.o1 + ax.o1); DO_CORNER(u, w01 * ax.w1);
      u = *(const uint4*)(tp + az.o1 + ay.o0 + ax.o0); DO_CORNER(u, w10 * ax.w0);
      u = *(const uint4*)(tp + az.o1 + ay.o0 + ax.o1); DO_CORNER(u, w10 * ax.w1);
      u = *(const uint4*)(tp + az.o1 + ay.o1 + ax.o0); DO_CORNER(u, w11 * ax.w0);
      u = *(const uint4*)(tp + az.o1 + ay.o1 + ax.o1); DO_CORNER(u, w11 * ax.w1);
    }
  }

  // phase 3: softmax over k (2048) per head
  float mx[8];
  #pragma unroll
  for (int h = 0; h < 8; ++h) {
    float m = fmaxf(fmaxf(acc[h][0], acc[h][1]), fmaxf(acc[h][2], acc[h][3]));
    #pragma unroll
    for (int off = 32; off >= 1; off >>= 1) m = fmaxf(m, __shfl_xor(m, off, 64));
    mx[h] = m;
  }
  if (l == 0) {
    #pragma unroll
    for (int h = 0; h < 8; ++h) red[h * 8 + wv] = mx[h];
  }
  __syncthreads();
  #pragma unroll
  for (int h = 0; h < 8; ++h) {
    float4 r0 = *(const float4*)&red[h * 8];
    float4 r1 = *(const float4*)&red[h * 8 + 4];
    mx[h] = fmaxf(fmaxf(fmaxf(r0.x, r0.y), fmaxf(r0.z, r0.w)),
                  fmaxf(fmaxf(r1.x, r1.y), fmaxf(r1.z, r1.w)));
  }
  __syncthreads();
  float sm[8];
  #pragma unroll
  for (int h = 0; h < 8; ++h) {
    acc[h][0] = __expf(acc[h][0] - mx[h]);
    acc[h][1] = __expf(acc[h][1] - mx[h]);
    acc[h][2] = __expf(acc[h][2] - mx[h]);
    acc[h][3] = __expf(acc[h][3] - mx[h]);
    float s = (acc[h][0] + acc[h][1]) + (acc[h][2] + acc[h][3]);
    #pragma unroll
    for (int off = 32; off >= 1; off >>= 1) s += __shfl_xor(s, off, 64);
    sm[h] = s;
  }
  if (l == 0) {
    #pragma unroll
    for (int h = 0; h < 8; ++h) red[h * 8 + wv] = sm[h];
  }
  __syncthreads();
  #pragma unroll
  for (int h = 0; h < 8; ++h) {
    float4 r0 = *(const float4*)&red[h * 8];
    float4 r1 = *(const float4*)&red[h * 8 + 4];
    float s = ((r0.x + r0.y) + (r0.z + r0.w)) + ((r1.x + r1.y) + (r1.z + r1.w));
    float inv = 1.f / s;
    float4 pv;
    pv.x = acc[h][0] * inv; pv.y = acc[h][1] * inv;
    pv.z = acc[h][2] * inv; pv.w = acc[h][3] * inv;
    *(float4*)&attn[((b * 8 + h) * 256 + q) * 2048 + k0] = pv;
  }
}

// ---------------- kernel 4: x = attn @ v (k-split partials) ----------------
#define AV_ACC(A, s, v) { (A).x = fmaf((s), (v).x, (A).x); (A).y = fmaf((s), (v).y, (A).y); \
                          (A).z = fmaf((s), (v).z, (A).z); (A).w = fmaf((s), (v).w, (A).w); }

__global__ __launch_bounds__(256) void k_av(const float* __restrict__ attn,
                                            const float* __restrict__ vp,
                                            float* __restrict__ xpart) {
  int bid = blockIdx.x;
  int kc = bid & 7, qt = (bid >> 3) & 3, h = (bid >> 5) & 7, b = bid >> 8;
  int t = threadIdx.x;
  int rq = t >> 3, rd = t & 7;
  int q0 = qt * 64 + rq * 2;
  int d0 = rd * 4;
  const float* ar0 = attn + ((b * 8 + h) * 256 + q0) * 2048;
  const float* ar1 = ar0 + 2048;
  const float* vbp = vp + b * NK * 32;
  float4 A0 = {0, 0, 0, 0}, A1 = {0, 0, 0, 0};
  for (int k = kc * 256; k < kc * 256 + 256; k += 4) {
    float4 a0 = *(const float4*)&ar0[k];
    float4 a1 = *(const float4*)&ar1[k];
    float4 v0 = *(const float4*)&vbp[(k + 0) * 32 + d0];
    float4 v1 = *(const float4*)&vbp[(k + 1) * 32 + d0];
    float4 v2 = *(const float4*)&vbp[(k + 2) * 32 + d0];
    float4 v3 = *(const float4*)&vbp[(k + 3) * 32 + d0];
    AV_ACC(A0, a0.x, v0) AV_ACC(A0, a0.y, v1) AV_ACC(A0, a0.z, v2) AV_ACC(A0, a0.w, v3)
    AV_ACC(A1, a1.x, v0) AV_ACC(A1, a1.y, v1) AV_ACC(A1, a1.z, v2) AV_ACC(A1, a1.w, v3)
  }
  int o = ((b * 8 + h) * 256 + q0) * 32 + d0;
  *(float4*)&xpart[kc * 131072 + o] = A0;
  *(float4*)&xpart[kc * 131072 + o + 32] = A1;
}

// ---------------- kernel 5: reduce partials + output proj ----------------
__global__ __launch_bounds__(256) void k_out(const float* __restrict__ xpart,
                                             const float* __restrict__ pw,
                                             const float* __restrict__ pb,
                                             float* __restrict__ out) {
  __shared__ float xr[4][257];
  int b = blockIdx.x >> 6, qc = blockIdx.x & 63, t = threadIdx.x;
  for (int idx = t; idx < 1024; idx += 256) {
    int r = idx >> 8, m = idx & 255;
    int q = qc * 4 + r, h = m >> 5, d = m & 31;
    int o = ((b * 8 + h) * 256 + q) * 32 + d;
    float s = 0;
    #pragma unroll
    for (int kc = 0; kc < 8; ++kc) s += xpart[kc * 131072 + o];
    xr[r][m] = s;
  }
  __syncthreads();
  int r = t >> 6, c0 = (t & 63) * 4;
  float4 a = *(const float4*)&pb[c0];
  #pragma unroll 4
  for (int m = 0; m < 256; ++m) {
    float rv = xr[r][m];
    float4 w4 = *(const float4*)&pw[m * 256 + c0];
    a.x = fmaf(rv, w4.x, a.x); a.y = fmaf(rv, w4.y, a.y);
    a.z = fmaf(rv, w4.z, a.z); a.w = fmaf(rv, w4.w, a.w);
  }
  int q = qc * 4 + r;
  *(float4*)&out[(q * BB + b) * 256 + c0] = a;
}

// ---------------- launch ----------------
extern "C" void kernel_launch(void* const* d_in, const int* in_sizes, int n_in,
                              void* d_out, int out_size, void* d_ws, size_t ws_size,
                              hipStream_t stream) {
  const float* query = (const float*)d_in[0];
  const float* key   = (const float*)d_in[1];
  const float* refp  = (const float*)d_in[2];
  // d_in[3] reference_angle: unused by reference
  const float* xyz   = (const float*)d_in[4];
  const float* qw    = (const float*)d_in[5];
  const float* qb    = (const float*)d_in[6];
  const float* kw    = (const float*)d_in[7];
  const float* kb    = (const float*)d_in[8];
  const float* vw    = (const float*)d_in[9];
  const float* vb    = (const float*)d_in[10];
  const float* pw    = (const float*)d_in[11];
  const float* pb    = (const float*)d_in[12];
  const float* w1    = (const float*)d_in[13];
  const float* b1    = (const float*)d_in[14];
  const float* w2    = (const float*)d_in[15];

  char* ws = (char*)d_ws;
  u16*   tb    = (u16*)(ws + TB_OFF);
  float* qp    = (float*)(ws + QP_OFF);
  float* kpT   = (float*)(ws + KT_OFF);
  float* vp    = (float*)(ws + VP_OFF);
  float* xpart = (float*)(ws + XP_OFF);
  float* out   = (float*)d_out;
  float* attn  = out + 131072;  // second tuple output

  hipLaunchKernelGGL(k_tables, dim3(32),  dim3(256), 0, stream, w1, b1, w2, tb);
  hipLaunchKernelGGL(k_kv,     dim3(256), dim3(512), 0, stream, key, kw, kb, vw, vb, kpT, vp);
  hipLaunchKernelGGL(k_q,      dim3(128), dim3(256), 0, stream, query, qw, qb, qp);
  hipLaunchKernelGGL(k_main,   dim3(512), dim3(512), 0, stream, tb, qp, kpT, xyz, refp, attn);
  hipLaunchKernelGGL(k_av,     dim3(512), dim3(256), 0, stream, attn, vp, xpart);
  hipLaunchKernelGGL(k_out,    dim3(128), dim3(256), 0, stream, xpart, pw, pb, out);
}